// Round 3
// baseline (246.437 us; speedup 1.0000x reference)
//
#include <hip/hip_runtime.h>
#include <cstddef>
#include <cstdint>

// SpatialPatchMoE on MI355X (gfx950).
// x[2,64,8,128,128] f32 -> 512 patches x 8 l-slices; router top-2/8;
// per expert: dwconv(1,7,7) -> LN(8,8) -> pw 64->128 -> silu*gate -> pw 64->64;
// out = x + sum_k w_k * expert_k.  Pointwise matmuls = bf16 MFMA 16x16x32.
//
// ws layout (bytes):
//   partial4 : [b][lp][p][c] f32   @ 0        (524288)
//   dwT      : [e][tap][c] f32     @ 524288   (100352)
//   sel_i    : int[2*512]          @ 624640   (4096)
//   sel_w    : f32[2*512]          @ 628736   (4096)
//   wInBf    : bf16 [e][128][64]   @ 632832   (131072)
//   wOutBf   : bf16 [e][64][64]    @ 763904   (65536)
//   xr       : f32 [n*8+l][c][px]  @ 829440   (67108864)   (repack path only)

typedef __attribute__((ext_vector_type(8))) short short8;
typedef __attribute__((ext_vector_type(4))) float f32x4;

#define H_STRIDE 72          // bf16 per pixel row of h/h3 (144 B, 16B-aligned)
#define REPACK_NEED 67938304ull

__device__ __forceinline__ unsigned short f2bf(float f) {
  unsigned u = __builtin_bit_cast(unsigned, f);
  unsigned r = (u + 0x7FFFu + ((u >> 16) & 1u)) >> 16;
  return (unsigned short)r;
}

__device__ __forceinline__ float wave_sum64(float v) {
#pragma unroll
  for (int m = 32; m > 0; m >>= 1) v += __shfl_xor(v, m, 64);
  return v;
}

// ---------------- preprocess: dw transpose + pw weights -> bf16
__global__ void k_pre(const float* __restrict__ dw,
                      const float* __restrict__ pwin,
                      const float* __restrict__ pwout,
                      float* __restrict__ dwT,
                      unsigned short* __restrict__ wIn,
                      unsigned short* __restrict__ wOut) {
  int idx = blockIdx.x * 256 + threadIdx.x;
  if (idx < 25088) {
    int e = idx / 3136;
    int r = idx - e * 3136;
    int c = r / 49;
    int tap = r - c * 49;
    dwT[(e * 49 + tap) * 64 + c] = dw[idx];
  } else if (idx < 25088 + 65536) {
    int i = idx - 25088;
    wIn[i] = f2bf(pwin[i]);
  } else if (idx < 25088 + 65536 + 32768) {
    int i = idx - 90624;
    wOut[i] = f2bf(pwout[i]);
  }
}

// ---------------- patch sums (deterministic)
__global__ __launch_bounds__(256) void k_sum(const float* __restrict__ x,
                                             float* __restrict__ partial4) {
  __shared__ float red[256 * 17];
  int t = threadIdx.x, bid = blockIdx.x;
  int b = bid >> 8, c = (bid >> 2) & 63, lp = bid & 3;
  float acc[16];
#pragma unroll
  for (int k = 0; k < 16; ++k) acc[k] = 0.f;
  const float4* x4 = (const float4*)x + ((size_t)((b * 64 + c) * 8) + lp * 2) * 4096;
#pragma unroll
  for (int l2 = 0; l2 < 2; ++l2)
#pragma unroll
    for (int k = 0; k < 16; ++k) {
      float4 v = x4[l2 * 4096 + k * 256 + t];
      acc[k] += v.x + v.y + v.z + v.w;
    }
  int pcol = (t & 31) >> 1;
  int slot = ((t & 1) << 3) | (t >> 5);
#pragma unroll
  for (int k = 0; k < 16; ++k) red[(k * 16 + pcol) * 17 + slot] = acc[k];
  __syncthreads();
  float s = 0.f;
#pragma unroll
  for (int j = 0; j < 16; ++j) s += red[t * 17 + j];
  partial4[((size_t)(b * 4 + lp) * 256 + t) * 64 + c] = s;
}

// ---------------- router
__global__ void k_router(const float* __restrict__ partial4,
                         const float* __restrict__ rw, const float* __restrict__ rb,
                         int* __restrict__ sel_i, float* __restrict__ sel_w) {
  int n = blockIdx.x;
  int lane = threadIdx.x;
  int b = n >> 8, p = n & 255;
  float s = 0.f;
#pragma unroll
  for (int lp = 0; lp < 4; ++lp)
    s += partial4[((size_t)(b * 4 + lp) * 256 + p) * 64 + lane];
  float rin = s * (1.f / 512.f);
  float lg[8];
#pragma unroll
  for (int e = 0; e < 8; ++e) {
    float v = rin * rw[e * 64 + lane];
    lg[e] = wave_sum64(v) + rb[e];
  }
  int e0 = 0; float v0 = lg[0];
#pragma unroll
  for (int e = 1; e < 8; ++e) if (lg[e] > v0) { v0 = lg[e]; e0 = e; }
  int e1 = -1; float v1 = -1e30f;
#pragma unroll
  for (int e = 0; e < 8; ++e) if (e != e0 && lg[e] > v1) { v1 = lg[e]; e1 = e; }
  if (lane == 0) {
    float w1 = __expf(v1 - v0);
    float z = 1.f + w1;
    sel_i[2 * n] = e0; sel_i[2 * n + 1] = e1;
    sel_w[2 * n] = 1.f / z; sel_w[2 * n + 1] = w1 / z;
  }
}

// ---------------- repack x -> patch-major xr[(n*8+l)][c][px]
__global__ __launch_bounds__(256) void k_repack(const float* __restrict__ x,
                                                float* __restrict__ xr) {
  // block = (b, l, hh); LDS rows stride 140 dwords, channel-tile stride 1124
  __shared__ __align__(16) float lt[16 * 1124];
  int t = threadIdx.x, bid = blockIdx.x;
  int b = bid >> 7, l = (bid >> 4) & 7, hh = bid & 15;
  const float4* x4 = (const float4*)x;
  float4* xr4 = (float4*)xr;
  int y = t >> 5, xq = t & 31;
  int cc = t >> 4, pxq = t & 15, py = pxq >> 1, xcol = pxq & 1;
#pragma unroll 1
  for (int ct = 0; ct < 4; ++ct) {
    int c0 = ct * 16;
    __syncthreads();  // protect lt reuse across tiles
#pragma unroll
    for (int i = 0; i < 16; ++i) {   // i = channel within tile
      size_t src = ((size_t)((b * 64 + c0 + i) * 8 + l) << 12) +
                   (size_t)(hh * 8 + y) * 32 + xq;
      float4 v = x4[src];
      *(float4*)(lt + i * 1124 + y * 140 + xq * 4) = v;
    }
    __syncthreads();
#pragma unroll
    for (int i = 0; i < 16; ++i) {   // i = patch ww
      float4 v = *(const float4*)(lt + cc * 1124 + py * 140 + i * 8 + xcol * 4);
      int n = b * 256 + hh * 16 + i;
      xr4[((size_t)(n * 8 + l) << 10) + (c0 + cc) * 16 + pxq] = v;
    }
  }
}

// ---------------- depthwise conv: wave owns output rows Y0, Y0+1; weights in LDS
template <int Y0>
__device__ __forceinline__ void convRows(const float* __restrict__ rowp,
                                         const float* __restrict__ wl,
                                         float* __restrict__ hv) {
  constexpr int RLO = (Y0 - 3 < 0) ? 0 : Y0 - 3;
  constexpr int RHI = (Y0 + 4 > 7) ? 7 : Y0 + 4;
#pragma unroll
  for (int r = RLO; r <= RHI; ++r) {
    float4 ra = *(const float4*)(rowp + r * 8);
    float4 rbv = *(const float4*)(rowp + r * 8 + 4);
    const float row[8] = {ra.x, ra.y, ra.z, ra.w, rbv.x, rbv.y, rbv.z, rbv.w};
#pragma unroll
    for (int ry = 0; ry < 2; ++ry) {
      const int dy = r - (Y0 + ry) + 3;
      if (dy >= 0 && dy <= 6) {
#pragma unroll
        for (int dx = 0; dx < 7; ++dx) {
          float wt = wl[(dy * 7 + dx) * 64];
#pragma unroll
          for (int xp = 0; xp < 8; ++xp) {
            const int xx = xp + dx - 3;
            if (xx >= 0 && xx < 8) hv[ry * 8 + xp] += row[xx] * wt;
          }
        }
      }
    }
  }
}

// ---------------- main: one block per (patch n, depth l); 4 waves
template <bool REPACK>
__global__ __launch_bounds__(256) void k_main(
    const float* __restrict__ x, const float* __restrict__ xr,
    const float* __restrict__ dwT, const float* __restrict__ dwb,
    const float* __restrict__ lnw, const float* __restrict__ lnb,
    const float* __restrict__ pwin_b, const float* __restrict__ pwout_b,
    const unsigned short* __restrict__ wInBf,
    const unsigned short* __restrict__ wOutBf,
    const int* __restrict__ sel_i, const float* __restrict__ sel_w,
    float* __restrict__ out) {
  // smem carve: wsdw f32[3136] | hbf u16[64*72] | h3bf u16[64*72] | lnred f32[512] | (xs f32[64*68] fallback)
  constexpr int SMBYTES = REPACK ? 33024 : 50432;
  __shared__ __align__(16) char smem[SMBYTES];
  float* wsdw          = (float*)smem;
  unsigned short* hbf  = (unsigned short*)(smem + 12544);
  unsigned short* h3bf = (unsigned short*)(smem + 21760);
  float* lnred         = (float*)(smem + 30976);
  float* xs            = (float*)(smem + 33024);   // fallback only

  const int t = threadIdx.x;
  const int lane = t & 63;
  const int wv = __builtin_amdgcn_readfirstlane(t >> 6);
  const int r15 = lane & 15, r4 = lane >> 4;
  const int bidx = blockIdx.x;
  const int n = bidx >> 3, l = bidx & 7;
  const int b = n >> 8, p = n & 255;
  const int hh = p >> 4, ww = p & 15;
  const size_t obase = (size_t)b * 8388608 + (size_t)l * 16384 +
                       (size_t)hh * 1024 + (size_t)ww * 8;

  if constexpr (!REPACK) {
    // stage x slice -> xs [c][px], stride 68
#pragma unroll
    for (int i = 0; i < 4; ++i) {
      int g = i * 256 + t;
      int hf = g & 1, y = (g >> 1) & 7, c = g >> 4;
      float4 v = *(const float4*)(x + obase + (size_t)c * 131072 + y * 128 + hf * 4);
      *(float4*)(xs + c * 68 + y * 8 + hf * 4) = v;
    }
  }

  float oacc[16];
#pragma unroll
  for (int i = 0; i < 16; ++i) oacc[i] = 0.f;

#pragma unroll 1
  for (int k = 0; k < 2; ++k) {
    const int e = __builtin_amdgcn_readfirstlane(sel_i[2 * n + k]);
    const float we = sel_w[2 * n + k];

    // ---- stage this expert's dw weights into LDS (784 float4)
    {
      const float4* src = (const float4*)(dwT + e * 3136);
      float4* dst = (float4*)wsdw;
      if (t < 196) {
#pragma unroll
        for (int i = 0; i < 4; ++i) dst[i * 196 + t] = src[i * 196 + t];
      }
    }
    __syncthreads();  // syncW: wsdw ready (also orders xs staging / prev-iter h3 reads)

    // ---- depthwise conv: lane = channel
    float hv[16];
    {
      const float bias = dwb[e * 64 + lane];
#pragma unroll
      for (int j = 0; j < 16; ++j) hv[j] = bias;
    }
    const float* wl = wsdw + lane;
    if constexpr (REPACK) {
      const float* rowp = xr + (size_t)bidx * 4096 + lane * 64;
      if (wv == 0)      convRows<0>(rowp, wl, hv);
      else if (wv == 1) convRows<2>(rowp, wl, hv);
      else if (wv == 2) convRows<4>(rowp, wl, hv);
      else              convRows<6>(rowp, wl, hv);
    } else {
      const float* rowp = xs + lane * 68;
      if (wv == 0)      convRows<0>(rowp, wl, hv);
      else if (wv == 1) convRows<2>(rowp, wl, hv);
      else if (wv == 2) convRows<4>(rowp, wl, hv);
      else              convRows<6>(rowp, wl, hv);
    }

    // ---- LayerNorm over 64 pixels per channel
    float ps = 0.f, pq = 0.f;
#pragma unroll
    for (int j = 0; j < 16; ++j) { ps += hv[j]; pq += hv[j] * hv[j]; }
    lnred[(wv * 2 + 0) * 64 + lane] = ps;
    lnred[(wv * 2 + 1) * 64 + lane] = pq;
    __syncthreads();  // sync1
    float sm = lnred[0 * 64 + lane] + lnred[2 * 64 + lane] +
               lnred[4 * 64 + lane] + lnred[6 * 64 + lane];
    float sq = lnred[1 * 64 + lane] + lnred[3 * 64 + lane] +
               lnred[5 * 64 + lane] + lnred[7 * 64 + lane];
    float mu = sm * (1.f / 64.f);
    float var = sq * (1.f / 64.f) - mu * mu;
    float rstd = rsqrtf(var + 1e-5f);
#pragma unroll
    for (int j = 0; j < 16; ++j) {
      int s = 16 * wv + j;  // pixel index (wave wv's rows 2wv..2wv+1)
      float nv = (hv[j] - mu) * rstd * lnw[e * 64 + s] + lnb[e * 64 + s];
      hbf[s * H_STRIDE + lane] = f2bf(nv);  // h[px][c] bf16
    }
    __syncthreads();  // sync2: h ready

    // ---- pw_in (64->128) via MFMA; silu*gate -> h3
    const unsigned short* wInE = wInBf + (size_t)e * 8192;
    short8 aA[2], aG[2];
#pragma unroll
    for (int kf = 0; kf < 2; ++kf) {
      aA[kf] = *(const short8*)(wInE + (16 * wv + r15) * 64 + kf * 32 + r4 * 8);
      aG[kf] = *(const short8*)(wInE + (64 + 16 * wv + r15) * 64 + kf * 32 + r4 * 8);
    }
    f32x4 accA[4], accG[4];
#pragma unroll
    for (int nt = 0; nt < 4; ++nt)
#pragma unroll
      for (int v = 0; v < 4; ++v) {
        accA[nt][v] = pwin_b[e * 128 + 16 * wv + r4 * 4 + v];
        accG[nt][v] = pwin_b[e * 128 + 64 + 16 * wv + r4 * 4 + v];
      }
#pragma unroll
    for (int nt = 0; nt < 4; ++nt)
#pragma unroll
      for (int kf = 0; kf < 2; ++kf) {
        short8 bfr = *(const short8*)(hbf + (16 * nt + r15) * H_STRIDE + kf * 32 + r4 * 8);
        accA[nt] = __builtin_amdgcn_mfma_f32_16x16x32_bf16(aA[kf], bfr, accA[nt], 0, 0, 0);
        accG[nt] = __builtin_amdgcn_mfma_f32_16x16x32_bf16(aG[kf], bfr, accG[nt], 0, 0, 0);
      }
#pragma unroll
    for (int nt = 0; nt < 4; ++nt)
#pragma unroll
      for (int v = 0; v < 4; ++v) {
        float a = accA[nt][v];
        float g = accG[nt][v];
        float hval = (a / (1.f + __expf(-a))) * g;
        h3bf[(16 * nt + r15) * H_STRIDE + 16 * wv + r4 * 4 + v] = f2bf(hval);
      }
    __syncthreads();  // sync3: h3 ready

    // ---- pw_out (64->64) via MFMA
    const unsigned short* wOutE = wOutBf + (size_t)e * 4096;
    short8 aO[2];
#pragma unroll
    for (int kf = 0; kf < 2; ++kf)
      aO[kf] = *(const short8*)(wOutE + (16 * wv + r15) * 64 + kf * 32 + r4 * 8);
    f32x4 accO[4];
#pragma unroll
    for (int nt = 0; nt < 4; ++nt)
#pragma unroll
      for (int v = 0; v < 4; ++v) accO[nt][v] = 0.f;
#pragma unroll
    for (int nt = 0; nt < 4; ++nt)
#pragma unroll
      for (int kf = 0; kf < 2; ++kf) {
        short8 bfr = *(const short8*)(h3bf + (16 * nt + r15) * H_STRIDE + kf * 32 + r4 * 8);
        accO[nt] = __builtin_amdgcn_mfma_f32_16x16x32_bf16(aO[kf], bfr, accO[nt], 0, 0, 0);
      }
    float bO[4];
#pragma unroll
    for (int v = 0; v < 4; ++v) bO[v] = pwout_b[e * 64 + 16 * wv + r4 * 4 + v];
#pragma unroll
    for (int nt = 0; nt < 4; ++nt)
#pragma unroll
      for (int v = 0; v < 4; ++v) oacc[nt * 4 + v] += we * (accO[nt][v] + bO[v]);
  }

  // ---- epilogue: oacc -> LDS (f32 [c][px] stride 68, aliasing hbf+h3bf), then
  //      vectorized residual + store
  float* eb = (float*)(smem + 12544);
  __syncthreads();  // pw_out h3bf reads done before aliasing write
#pragma unroll
  for (int nt = 0; nt < 4; ++nt)
#pragma unroll
    for (int v = 0; v < 4; ++v)
      eb[(16 * wv + 4 * r4 + v) * 68 + 16 * nt + r15] = oacc[nt * 4 + v];
  __syncthreads();
#pragma unroll
  for (int i = 0; i < 4; ++i) {
    int g = i * 256 + t;
    int c = g >> 4, py = (g >> 1) & 7, half = g & 1;
    float4 dv = *(const float4*)(eb + c * 68 + py * 8 + half * 4);
    float4 xv;
    if constexpr (REPACK)
      xv = *(const float4*)(xr + (size_t)bidx * 4096 + (size_t)g * 4);
    else
      xv = *(const float4*)(xs + c * 68 + py * 8 + half * 4);
    float4 o4 = {xv.x + dv.x, xv.y + dv.y, xv.z + dv.z, xv.w + dv.w};
    *(float4*)(out + obase + (size_t)c * 131072 + py * 128 + half * 4) = o4;
  }
}

extern "C" void kernel_launch(void* const* d_in, const int* in_sizes, int n_in,
                              void* d_out, int out_size, void* d_ws, size_t ws_size,
                              hipStream_t stream) {
  const float* x       = (const float*)d_in[0];
  const float* rw      = (const float*)d_in[1];
  const float* rb      = (const float*)d_in[2];
  const float* dww     = (const float*)d_in[3];
  const float* dwb     = (const float*)d_in[4];
  const float* lnw     = (const float*)d_in[5];
  const float* lnb     = (const float*)d_in[6];
  const float* pwin_w  = (const float*)d_in[7];
  const float* pwin_b  = (const float*)d_in[8];
  const float* pwout_w = (const float*)d_in[9];
  const float* pwout_b = (const float*)d_in[10];
  float* out = (float*)d_out;

  char* ws = (char*)d_ws;
  float*          partial4 = (float*)ws;
  float*          dwT      = (float*)(ws + 524288);
  int*            sel_i    = (int*)(ws + 624640);
  float*          sel_w    = (float*)(ws + 628736);
  unsigned short* wInBf    = (unsigned short*)(ws + 632832);
  unsigned short* wOutBf   = (unsigned short*)(ws + 763904);
  float*          xr       = (float*)(ws + 829440);

  const bool repack = ws_size >= REPACK_NEED;

  hipLaunchKernelGGL(k_pre,    dim3(482), dim3(256), 0, stream,
                     dww, pwin_w, pwout_w, dwT, wInBf, wOutBf);
  hipLaunchKernelGGL(k_sum,    dim3(512), dim3(256), 0, stream, x, partial4);
  if (repack)
    hipLaunchKernelGGL(k_repack, dim3(256), dim3(256), 0, stream, x, xr);
  hipLaunchKernelGGL(k_router, dim3(512), dim3(64), 0, stream,
                     partial4, rw, rb, sel_i, sel_w);
  if (repack)
    hipLaunchKernelGGL((k_main<true>), dim3(4096), dim3(256), 0, stream,
                       x, xr, dwT, dwb, lnw, lnb, pwin_b, pwout_b,
                       wInBf, wOutBf, sel_i, sel_w, out);
  else
    hipLaunchKernelGGL((k_main<false>), dim3(4096), dim3(256), 0, stream,
                       x, xr, dwT, dwb, lnw, lnb, pwin_b, pwout_b,
                       wInBf, wOutBf, sel_i, sel_w, out);
}